// Round 2
// baseline (25.642 us; speedup 1.0000x reference)
//
#include <hip/hip_runtime.h>
#include <hip/hip_bf16.h>

// WithLSHSort reduces to the identity:
//   idx = argsort(angles) is a permutation along S per (b, h);
//   inv = argsort(idx) is its exact inverse permutation;
//   gather(gather(x, idx), inv) == x  (exactly, independent of the angles).
// Therefore out = x. Pure D2D copy of 64 MiB fp32.
//
// Round 1: hipMemcpyAsync blit = 24.5 us (5.49 TB/s). Hand-rolled float4
// grid-stride copy targets the 6.29 TB/s float4-copy ceiling (~21.3 us).

__global__ __launch_bounds__(256) void copy_f4(const float4* __restrict__ src,
                                               float4* __restrict__ dst,
                                               int n4) {
    int stride = gridDim.x * blockDim.x;
    for (int i = blockIdx.x * blockDim.x + threadIdx.x; i < n4; i += stride) {
        dst[i] = src[i];
    }
}

extern "C" void kernel_launch(void* const* d_in, const int* in_sizes, int n_in,
                              void* d_out, int out_size, void* d_ws, size_t ws_size,
                              hipStream_t stream) {
    const float4* x = (const float4*)d_in[0];
    float4* out = (float4*)d_out;
    int n4 = out_size / 4;  // 16,777,216 floats -> 4,194,304 float4
    // 2048 blocks x 256 threads = 524,288 threads; exactly 8 float4 each.
    copy_f4<<<2048, 256, 0, stream>>>(x, out, n4);
}

// Round 4
// 24.674 us; speedup vs baseline: 1.0392x; 1.0392x over previous
//
#include <hip/hip_runtime.h>
#include <hip/hip_bf16.h>

// WithLSHSort reduces to the identity:
//   idx = argsort(angles) is a permutation along S per (b, h);
//   inv = argsort(idx) is its exact inverse permutation;
//   gather(gather(x, idx), inv) == x  (exactly, independent of the angles).
// Therefore out = x. Pure D2D copy of 64 MiB fp32.
//
// R1: hipMemcpyAsync blit = 24.5 us (5.49 TB/s).
// R2: 2048-block grid-stride float4 = 25.6 us (worse; loop overhead).
// R3: nontemporal builtins reject HIP_vector_type -> use clang
//     ext_vector_type(4) float. One float4/thread, 16384 blocks.

typedef float f32x4 __attribute__((ext_vector_type(4)));

__global__ __launch_bounds__(256) void copy_f4_nt(const f32x4* __restrict__ src,
                                                  f32x4* __restrict__ dst) {
    int i = blockIdx.x * 256 + threadIdx.x;
    f32x4 v = __builtin_nontemporal_load(&src[i]);
    __builtin_nontemporal_store(v, &dst[i]);
}

extern "C" void kernel_launch(void* const* d_in, const int* in_sizes, int n_in,
                              void* d_out, int out_size, void* d_ws, size_t ws_size,
                              hipStream_t stream) {
    const f32x4* x = (const f32x4*)d_in[0];
    f32x4* out = (f32x4*)d_out;
    int n4 = out_size / 4;          // 4,194,304 float4 (exact multiple of 256)
    int blocks = n4 / 256;          // 16384 blocks, one float4 per thread
    copy_f4_nt<<<blocks, 256, 0, stream>>>(x, out);
}